// Round 8
// baseline (3727.275 us; speedup 1.0000x reference)
//
#include <hip/hip_runtime.h>

#define N_NODES 100000
#define N_EDGES 3200000
#define NFEAT 512
#define NHID 256
#define NCLASS 64
#define FCAT 128   // 2*NCLASS

#define RPB 64                         // rows per bucket
#define NB 1563                        // ceil(N_NODES / RPB)
#define CHUNK 8192                     // edges per partition block
#define NCH 391                        // ceil(N_EDGES / CHUNK)

typedef __attribute__((ext_vector_type(8))) short short8;
typedef __attribute__((ext_vector_type(4))) float f32x4;

static __device__ __forceinline__ unsigned short f2bf(float f) {
    unsigned u = __float_as_uint(f);
    unsigned r = (u + 0x7FFF + ((u >> 16) & 1)) >> 16;  // RNE
    return (unsigned short)r;
}
static __device__ __forceinline__ float bf2f(unsigned s) {
    return __uint_as_float(s << 16);
}
static __device__ __forceinline__ short8 cvt8(float4 x, float4 y) {
    short8 r;
    r[0] = (short)f2bf(x.x); r[1] = (short)f2bf(x.y);
    r[2] = (short)f2bf(x.z); r[3] = (short)f2bf(x.w);
    r[4] = (short)f2bf(y.x); r[5] = (short)f2bf(y.y);
    r[6] = (short)f2bf(y.z); r[7] = (short)f2bf(y.w);
    return r;
}
__device__ __forceinline__ void gload_lds16(const unsigned short* g, unsigned short* l) {
    __builtin_amdgcn_global_load_lds(
        (const __attribute__((address_space(1))) unsigned int*)g,
        (__attribute__((address_space(3))) unsigned int*)l, 16, 0, 0);
}

// ---------------------------------------------------------------------------
// Weight prep
// ---------------------------------------------------------------------------
__global__ void k_prep_wcat(const float* __restrict__ W1, const float* __restrict__ W2,
                            const float* __restrict__ Wres, unsigned short* __restrict__ WT) {
    int k = blockIdx.x;        // 0..511
    int j = threadIdx.x;       // 0..127
    const float* wb = (j < NCLASS) ? W2 : Wres;
    int jj = j & (NCLASS - 1);
    const float* w1row = W1 + (size_t)k * NHID;
    float acc = 0.f;
    for (int m = 0; m < NHID; ++m)
        acc += w1row[m] * wb[(size_t)m * NCLASS + jj];
    WT[(size_t)j * NFEAT + k] = f2bf(acc);
}

__global__ void k_prep_c(const float* __restrict__ b1, const float* __restrict__ W2,
                         const float* __restrict__ Wres, const float* __restrict__ bres,
                         float* __restrict__ c2, float* __restrict__ cr) {
    int j = threadIdx.x;  // 0..127
    const float* wb = (j < NCLASS) ? W2 : Wres;
    int jj = j & (NCLASS - 1);
    float acc = 0.f;
    for (int m = 0; m < NHID; ++m)
        acc += b1[m] * wb[(size_t)m * NCLASS + jj];
    if (j < NCLASS) c2[jj] = acc;
    else            cr[jj] = acc + bres[jj];
}

// ---------------------------------------------------------------------------
// MFMA GEMM: A_bf16[N,128] = bf16(X[N,512] @ Wcat[512,128])
// Direct-A from global f32; B double-buffered in LDS via global_load_lds,
// XOR-swizzled (pre-swizzled source, swizzled ds_read). 1 barrier/step.
// ---------------------------------------------------------------------------
#define GBK 64
__global__ __launch_bounds__(256) void k_gemm_a(const float* __restrict__ X,
                                                const unsigned short* __restrict__ WT,
                                                unsigned short* __restrict__ A) {
    __shared__ __align__(16) unsigned short Bs[2][FCAT * GBK];  // 2 x 16 KB
    int tid = threadIdx.x;
    int lane = tid & 63, w = tid >> 6;
    int lr = lane & 15, ls = lane >> 4;
    int row = blockIdx.x * 64 + w * 16 + lr;
    if (row >= N_NODES) row = N_NODES - 1;  // tail clamp (loads only)
    const float* pA = X + (size_t)row * NFEAT;

#define STAGE(buf, k0)                                                         \
    {                                                                          \
        _Pragma("unroll")                                                      \
        for (int q = 0; q < 4; ++q) {                                          \
            int sidx = q * 256 + tid;                                          \
            int n = sidx >> 3, c8 = sidx & 7;                                  \
            const unsigned short* src =                                        \
                WT + (size_t)n * NFEAT + (k0) + ((c8 ^ (n & 7)) << 3);         \
            unsigned short* dst = &Bs[buf][(size_t)(q * 256 + w * 64) * 8];    \
            gload_lds16(src, dst);                                             \
        }                                                                      \
    }

    f32x4 acc[8] = {};
    STAGE(0, 0);
    __syncthreads();
    int cur = 0;

#pragma unroll
    for (int t = 0; t < 8; ++t) {
        const int k0 = t * GBK;
        float4 a00 = *(const float4*)(pA + k0 + ls * 8);
        float4 a01 = *(const float4*)(pA + k0 + ls * 8 + 4);
        float4 a10 = *(const float4*)(pA + k0 + 32 + ls * 8);
        float4 a11 = *(const float4*)(pA + k0 + 32 + ls * 8 + 4);
        if (t < 7) STAGE(cur ^ 1, k0 + GBK);

        short8 af0 = cvt8(a00, a01);
        short8 af1 = cvt8(a10, a11);
        const unsigned short* bb = &Bs[cur][0];
#pragma unroll
        for (int nf = 0; nf < 8; ++nf) {
            int n = nf * 16 + lr;
            int p0 = ls ^ (n & 7);
            int p1 = (4 + ls) ^ (n & 7);
            short8 b0 = *(const short8*)(bb + (size_t)n * 64 + p0 * 8);
            short8 b1 = *(const short8*)(bb + (size_t)n * 64 + p1 * 8);
            acc[nf] = __builtin_amdgcn_mfma_f32_16x16x32_bf16(af0, b0, acc[nf], 0, 0, 0);
            acc[nf] = __builtin_amdgcn_mfma_f32_16x16x32_bf16(af1, b1, acc[nf], 0, 0, 0);
        }
        __syncthreads();
        cur ^= 1;
    }
#undef STAGE

    // C/D layout: col = lane&15, row = (lane>>4)*4 + j
#pragma unroll
    for (int j = 0; j < 4; ++j) {
        int gr = blockIdx.x * 64 + w * 16 + ls * 4 + j;
        if (gr < N_NODES) {
#pragma unroll
            for (int nf = 0; nf < 8; ++nf)
                A[(size_t)gr * FCAT + nf * 16 + lr] = f2bf(acc[nf][j]);
        }
    }
}

// ---------------------------------------------------------------------------
// CSR build — atomic-free radix partition into 64-row buckets (no row sort)
// ---------------------------------------------------------------------------
__global__ __launch_bounds__(256) void k_hist_bkt(const int* __restrict__ rows,
                                                  int* __restrict__ HT) {
    __shared__ int h[NB];
    int c = blockIdx.x;
    for (int i = threadIdx.x; i < NB; i += 256) h[i] = 0;
    __syncthreads();
    int e0 = c * CHUNK;
    int eend = e0 + CHUNK; if (eend > N_EDGES) eend = N_EDGES;
    for (int e = e0 + threadIdx.x; e < eend; e += 256)
        atomicAdd(&h[rows[e] >> 6], 1);
    __syncthreads();
    for (int i = threadIdx.x; i < NB; i += 256)
        HT[(size_t)i * NCH + c] = h[i];
}

__global__ void k_scan_chunks(const int* __restrict__ HT, int* __restrict__ OFS,
                              int* __restrict__ T) {
    int b = blockIdx.x;
    int lane = threadIdx.x;  // 64
    const int* hb = HT + (size_t)b * NCH;
    int run = 0;
    for (int c0 = 0; c0 < NCH; c0 += 64) {
        int idx = c0 + lane;
        int v = (idx < NCH) ? hb[idx] : 0;
        int inc = v;
#pragma unroll
        for (int d = 1; d < 64; d <<= 1) {
            int t = __shfl_up(inc, d);
            if (lane >= d) inc += t;
        }
        if (idx < NCH) OFS[(size_t)idx * NB + b] = run + inc - v;
        run += __shfl(inc, 63);
    }
    if (lane == 0) T[b] = run;
}

__global__ void k_scan_base(const int* __restrict__ T, int* __restrict__ base) {
    int lane = threadIdx.x;  // 64
    int run = 0;
    for (int c0 = 0; c0 < NB; c0 += 64) {
        int idx = c0 + lane;
        int v = (idx < NB) ? T[idx] : 0;
        int inc = v;
#pragma unroll
        for (int d = 1; d < 64; d <<= 1) {
            int t = __shfl_up(inc, d);
            if (lane >= d) inc += t;
        }
        if (idx < NB) base[idx] = run + inc - v;
        run += __shfl(inc, 63);
    }
    if (lane == 0) base[NB] = run;
}

__global__ __launch_bounds__(256) void k_partition(const int* __restrict__ rows,
                                                   const int* __restrict__ cols,
                                                   const float* __restrict__ vals,
                                                   const int* __restrict__ OFS,
                                                   const int* __restrict__ base,
                                                   int2* __restrict__ stage) {
    __shared__ int cur[NB];
    int c = blockIdx.x;
    for (int i = threadIdx.x; i < NB; i += 256)
        cur[i] = base[i] + OFS[(size_t)c * NB + i];
    __syncthreads();
    int e0 = c * CHUNK;
    int eend = e0 + CHUNK; if (eend > N_EDGES) eend = N_EDGES;
    for (int e = e0 + threadIdx.x; e < eend; e += 256) {
        int r = rows[e];
        int p = atomicAdd(&cur[r >> 6], 1);
        stage[p] = make_int2(((r & 63) << 17) | cols[e], __float_as_int(vals[e]));
    }
}

// ---------------------------------------------------------------------------
// SpMM 1 over bucket-staged edges: block = bucket, LDS f32 accumulators,
// fire-and-forget ds_add. Gathers bf16 A rows (256 B/edge), 8-deep MLP.
// ---------------------------------------------------------------------------
__global__ __launch_bounds__(256) void k_spmm1(const unsigned* __restrict__ A32,
                                               const int* __restrict__ base,
                                               const int2* __restrict__ stage,
                                               unsigned* __restrict__ S1a,
                                               float2* __restrict__ S1r) {
    __shared__ float acc[RPB][FCAT];  // 32 KB
    int b = blockIdx.x, tid = threadIdx.x;
    int wv = tid >> 6, lane = tid & 63;
    float4* az = (float4*)&acc[0][0];
    for (int i = tid; i < RPB * FCAT / 4; i += 256)
        az[i] = make_float4(0.f, 0.f, 0.f, 0.f);
    __syncthreads();

    int s = base[b], e = base[b + 1];
    int per = (e - s + 3) >> 2;
    int ws = s + wv * per;
    int we = ws + per; if (we > e) we = e;
    int t = ws;
    for (; t + 8 <= we; t += 8) {
        int2 cv[8];
#pragma unroll
        for (int u = 0; u < 8; ++u) cv[u] = stage[t + u];
        unsigned p[8];
#pragma unroll
        for (int u = 0; u < 8; ++u)
            p[u] = A32[(size_t)(cv[u].x & 0x1FFFF) * 64 + lane];
#pragma unroll
        for (int u = 0; u < 8; ++u) {
            float v = __int_as_float(cv[u].y);
            int rl = ((unsigned)cv[u].x) >> 17;
            atomicAdd(&acc[rl][lane * 2], v * bf2f(p[u] & 0xffffu));
            atomicAdd(&acc[rl][lane * 2 + 1], v * bf2f(p[u] >> 16));
        }
    }
    for (; t < we; ++t) {
        int2 cv = stage[t];
        unsigned p = A32[(size_t)(cv.x & 0x1FFFF) * 64 + lane];
        float v = __int_as_float(cv.y);
        int rl = ((unsigned)cv.x) >> 17;
        atomicAdd(&acc[rl][lane * 2], v * bf2f(p & 0xffffu));
        atomicAdd(&acc[rl][lane * 2 + 1], v * bf2f(p >> 16));
    }
    __syncthreads();

#pragma unroll
    for (int rr = 0; rr < 16; ++rr) {
        int r = wv * 16 + rr;
        int node = b * RPB + r;
        if (node < N_NODES) {
            if (lane < 32) {
                S1a[(size_t)node * 32 + lane] =
                    (unsigned)f2bf(acc[r][lane * 2]) |
                    ((unsigned)f2bf(acc[r][lane * 2 + 1]) << 16);
            } else {
                int m = lane - 32;
                S1r[(size_t)node * 32 + m] =
                    make_float2(acc[r][64 + m * 2], acc[r][64 + m * 2 + 1]);
            }
        }
    }
}

// ---------------------------------------------------------------------------
// SpMM 2 + fused epilogue over bucket-staged edges (gathers bf16 S1a rows,
// 128 B/edge), LDS accumulators + per-row rsum.
// ---------------------------------------------------------------------------
__global__ __launch_bounds__(256) void k_spmm2_out(const unsigned short* __restrict__ S1a16,
                                                   const float* __restrict__ S1r,
                                                   const int* __restrict__ base,
                                                   const int2* __restrict__ stage,
                                                   const float* __restrict__ c2,
                                                   const float* __restrict__ cr,
                                                   const float* __restrict__ b2,
                                                   float* __restrict__ out) {
    __shared__ float acc[RPB][NCLASS];  // 16 KB
    __shared__ float rs[RPB];
    int b = blockIdx.x, tid = threadIdx.x;
    int wv = tid >> 6, lane = tid & 63;
    float4* az = (float4*)&acc[0][0];
    for (int i = tid; i < RPB * NCLASS / 4; i += 256)
        az[i] = make_float4(0.f, 0.f, 0.f, 0.f);
    if (tid < RPB) rs[tid] = 0.f;
    __syncthreads();

    int s = base[b], e = base[b + 1];
    int per = (e - s + 3) >> 2;
    int ws = s + wv * per;
    int we = ws + per; if (we > e) we = e;
    int t = ws;
    for (; t + 8 <= we; t += 8) {
        int2 cv[8];
#pragma unroll
        for (int u = 0; u < 8; ++u) cv[u] = stage[t + u];
        unsigned short p[8];
#pragma unroll
        for (int u = 0; u < 8; ++u)
            p[u] = S1a16[(size_t)(cv[u].x & 0x1FFFF) * 64 + lane];
#pragma unroll
        for (int u = 0; u < 8; ++u) {
            float v = __int_as_float(cv[u].y);
            int rl = ((unsigned)cv[u].x) >> 17;
            atomicAdd(&acc[rl][lane], v * bf2f((unsigned)p[u]));
            if (lane == 0) atomicAdd(&rs[rl], v);
        }
    }
    for (; t < we; ++t) {
        int2 cv = stage[t];
        float v = __int_as_float(cv.y);
        int rl = ((unsigned)cv.x) >> 17;
        unsigned short p = S1a16[(size_t)(cv.x & 0x1FFFF) * 64 + lane];
        atomicAdd(&acc[rl][lane], v * bf2f((unsigned)p));
        if (lane == 0) atomicAdd(&rs[rl], v);
    }
    __syncthreads();

#pragma unroll
    for (int rr = 0; rr < 16; ++rr) {
        int r = wv * 16 + rr;
        int node = b * RPB + r;
        if (node < N_NODES) {
            float o = acc[r][lane] + rs[r] * c2[lane] + b2[lane];
            float res = S1r[(size_t)node * 64 + lane] + cr[lane];
            out[(size_t)node * 64 + lane] = fmaxf(o, 0.f) + res;
        }
    }
}

// ---------------------------------------------------------------------------
extern "C" void kernel_launch(void* const* d_in, const int* in_sizes, int n_in,
                              void* d_out, int out_size, void* d_ws, size_t ws_size,
                              hipStream_t stream) {
    const float* x        = (const float*)d_in[0];
    const int*   adj_rows = (const int*)d_in[1];
    const int*   adj_cols = (const int*)d_in[2];
    const float* adj_vals = (const float*)d_in[3];
    const float* W1       = (const float*)d_in[4];
    const float* b1       = (const float*)d_in[5];
    const float* W2       = (const float*)d_in[6];
    const float* b2       = (const float*)d_in[7];
    const float* Wres     = (const float*)d_in[8];
    const float* bres     = (const float*)d_in[9];
    float* out = (float*)d_out;

    char* ws = (char*)d_ws;
    size_t off = 0;
    auto alloc = [&](size_t bytes) {
        size_t o = off;
        off += (bytes + 511) & ~511ULL;
        return o;
    };

    unsigned short* WT  = (unsigned short*)(ws + alloc((size_t)NFEAT * FCAT * 2));
    float* c2           = (float*)(ws + alloc(NCLASS * 4));
    float* cr           = (float*)(ws + alloc(NCLASS * 4));
    int2* stage         = (int2*)(ws + alloc((size_t)N_EDGES * 8));
    unsigned short* A   = (unsigned short*)(ws + alloc((size_t)N_NODES * FCAT * 2));
    unsigned* S1a       = (unsigned*)(ws + alloc((size_t)N_NODES * 32 * 4));
    // S1r region time-shares with HT/OFS (dead after k_partition)
    char* s1r_region    = ws + alloc((size_t)N_NODES * 64 * 4);
    float* S1r          = (float*)s1r_region;
    int*   HT           = (int*)s1r_region;
    int*   OFS          = (int*)(s1r_region + (((size_t)NB * NCH * 4 + 511) & ~511ULL));
    int*   T            = (int*)(ws + alloc((size_t)NB * 4));
    int*   base         = (int*)(ws + alloc((size_t)(NB + 1) * 4));
    (void)ws_size; (void)in_sizes; (void)n_in; (void)out_size;

    // weight prep (tiny)
    k_prep_wcat<<<NFEAT, FCAT, 0, stream>>>(W1, W2, Wres, WT);
    k_prep_c<<<1, FCAT, 0, stream>>>(b1, W2, Wres, bres, c2, cr);

    // bucket build: atomic-free radix partition (64-row buckets, no row sort)
    k_hist_bkt<<<NCH, 256, 0, stream>>>(adj_rows, HT);
    k_scan_chunks<<<NB, 64, 0, stream>>>(HT, OFS, T);
    k_scan_base<<<1, 64, 0, stream>>>(T, base);
    k_partition<<<NCH, 256, 0, stream>>>(adj_rows, adj_cols, adj_vals, OFS, base, stage);

    // dense MFMA GEMM: A = bf16(x @ Wcat)
    k_gemm_a<<<(N_NODES + 63) / 64, 256, 0, stream>>>(x, WT, A);

    // spmm 1: S1 = spmm(A)  (bf16 gather; overwrites HT/OFS region with S1r)
    k_spmm1<<<NB, 256, 0, stream>>>((const unsigned*)A, base, stage, S1a, (float2*)S1r);

    // spmm 2 + epilogue
    k_spmm2_out<<<NB, 256, 0, stream>>>((const unsigned short*)S1a, S1r, base, stage,
                                        c2, cr, b2, out);
}

// Round 9
// 406.465 us; speedup vs baseline: 9.1700x; 9.1700x over previous
//
#include <hip/hip_runtime.h>

#define N_NODES 100000
#define N_EDGES 3200000
#define NFEAT 512
#define NHID 256
#define NCLASS 64
#define FCAT 128   // 2*NCLASS

#define RPB 64                         // rows per bucket
#define NB 1563                        // ceil(N_NODES / RPB)
#define CHUNK 8192                     // edges per partition block
#define NCH 391                        // ceil(N_EDGES / CHUNK)

typedef __attribute__((ext_vector_type(8))) short short8;
typedef __attribute__((ext_vector_type(4))) float f32x4;

static __device__ __forceinline__ unsigned short f2bf(float f) {
    unsigned u = __float_as_uint(f);
    unsigned r = (u + 0x7FFF + ((u >> 16) & 1)) >> 16;  // RNE
    return (unsigned short)r;
}
static __device__ __forceinline__ float bf2f(unsigned s) {
    return __uint_as_float(s << 16);
}
static __device__ __forceinline__ short8 cvt8(float4 x, float4 y) {
    short8 r;
    r[0] = (short)f2bf(x.x); r[1] = (short)f2bf(x.y);
    r[2] = (short)f2bf(x.z); r[3] = (short)f2bf(x.w);
    r[4] = (short)f2bf(y.x); r[5] = (short)f2bf(y.y);
    r[6] = (short)f2bf(y.z); r[7] = (short)f2bf(y.w);
    return r;
}
__device__ __forceinline__ void gload_lds16(const unsigned short* g, unsigned short* l) {
    __builtin_amdgcn_global_load_lds(
        (const __attribute__((address_space(1))) unsigned int*)g,
        (__attribute__((address_space(3))) unsigned int*)l, 16, 0, 0);
}

// ---------------------------------------------------------------------------
// Weight prep
// ---------------------------------------------------------------------------
__global__ void k_prep_wcat(const float* __restrict__ W1, const float* __restrict__ W2,
                            const float* __restrict__ Wres, unsigned short* __restrict__ WT) {
    int k = blockIdx.x;        // 0..511
    int j = threadIdx.x;       // 0..127
    const float* wb = (j < NCLASS) ? W2 : Wres;
    int jj = j & (NCLASS - 1);
    const float* w1row = W1 + (size_t)k * NHID;
    float acc = 0.f;
    for (int m = 0; m < NHID; ++m)
        acc += w1row[m] * wb[(size_t)m * NCLASS + jj];
    WT[(size_t)j * NFEAT + k] = f2bf(acc);
}

__global__ void k_prep_c(const float* __restrict__ b1, const float* __restrict__ W2,
                         const float* __restrict__ Wres, const float* __restrict__ bres,
                         float* __restrict__ c2, float* __restrict__ cr) {
    int j = threadIdx.x;  // 0..127
    const float* wb = (j < NCLASS) ? W2 : Wres;
    int jj = j & (NCLASS - 1);
    float acc = 0.f;
    for (int m = 0; m < NHID; ++m)
        acc += b1[m] * wb[(size_t)m * NCLASS + jj];
    if (j < NCLASS) c2[jj] = acc;
    else            cr[jj] = acc + bres[jj];
}

// ---------------------------------------------------------------------------
// MFMA GEMM: A_bf16[N,128] = bf16(X[N,512] @ Wcat[512,128])
// Direct-A from global f32; B double-buffered in LDS via global_load_lds,
// XOR-swizzled (pre-swizzled source, swizzled ds_read). 1 barrier/step.
// ---------------------------------------------------------------------------
#define GBK 64
__global__ __launch_bounds__(256) void k_gemm_a(const float* __restrict__ X,
                                                const unsigned short* __restrict__ WT,
                                                unsigned short* __restrict__ A) {
    __shared__ __align__(16) unsigned short Bs[2][FCAT * GBK];  // 2 x 16 KB
    int tid = threadIdx.x;
    int lane = tid & 63, w = tid >> 6;
    int lr = lane & 15, ls = lane >> 4;
    int row = blockIdx.x * 64 + w * 16 + lr;
    if (row >= N_NODES) row = N_NODES - 1;  // tail clamp (loads only)
    const float* pA = X + (size_t)row * NFEAT;

#define STAGE(buf, k0)                                                         \
    {                                                                          \
        _Pragma("unroll")                                                      \
        for (int q = 0; q < 4; ++q) {                                          \
            int sidx = q * 256 + tid;                                          \
            int n = sidx >> 3, c8 = sidx & 7;                                  \
            const unsigned short* src =                                        \
                WT + (size_t)n * NFEAT + (k0) + ((c8 ^ (n & 7)) << 3);         \
            unsigned short* dst = &Bs[buf][(size_t)(q * 256 + w * 64) * 8];    \
            gload_lds16(src, dst);                                             \
        }                                                                      \
    }

    f32x4 acc[8] = {};
    STAGE(0, 0);
    __syncthreads();
    int cur = 0;

#pragma unroll
    for (int t = 0; t < 8; ++t) {
        const int k0 = t * GBK;
        float4 a00 = *(const float4*)(pA + k0 + ls * 8);
        float4 a01 = *(const float4*)(pA + k0 + ls * 8 + 4);
        float4 a10 = *(const float4*)(pA + k0 + 32 + ls * 8);
        float4 a11 = *(const float4*)(pA + k0 + 32 + ls * 8 + 4);
        if (t < 7) STAGE(cur ^ 1, k0 + GBK);

        short8 af0 = cvt8(a00, a01);
        short8 af1 = cvt8(a10, a11);
        const unsigned short* bb = &Bs[cur][0];
#pragma unroll
        for (int nf = 0; nf < 8; ++nf) {
            int n = nf * 16 + lr;
            int p0 = ls ^ (n & 7);
            int p1 = (4 + ls) ^ (n & 7);
            short8 b0 = *(const short8*)(bb + (size_t)n * 64 + p0 * 8);
            short8 b1 = *(const short8*)(bb + (size_t)n * 64 + p1 * 8);
            acc[nf] = __builtin_amdgcn_mfma_f32_16x16x32_bf16(af0, b0, acc[nf], 0, 0, 0);
            acc[nf] = __builtin_amdgcn_mfma_f32_16x16x32_bf16(af1, b1, acc[nf], 0, 0, 0);
        }
        __syncthreads();
        cur ^= 1;
    }
#undef STAGE

    // C/D layout: col = lane&15, row = (lane>>4)*4 + j
#pragma unroll
    for (int j = 0; j < 4; ++j) {
        int gr = blockIdx.x * 64 + w * 16 + ls * 4 + j;
        if (gr < N_NODES) {
#pragma unroll
            for (int nf = 0; nf < 8; ++nf)
                A[(size_t)gr * FCAT + nf * 16 + lr] = f2bf(acc[nf][j]);
        }
    }
}

// ---------------------------------------------------------------------------
// CSR build — atomic-free radix partition
// ---------------------------------------------------------------------------
__global__ __launch_bounds__(256) void k_hist_bkt(const int* __restrict__ rows,
                                                  int* __restrict__ HT) {
    __shared__ int h[NB];
    int c = blockIdx.x;
    for (int i = threadIdx.x; i < NB; i += 256) h[i] = 0;
    __syncthreads();
    int e0 = c * CHUNK;
    int eend = e0 + CHUNK; if (eend > N_EDGES) eend = N_EDGES;
    for (int e = e0 + threadIdx.x; e < eend; e += 256)
        atomicAdd(&h[rows[e] >> 6], 1);
    __syncthreads();
    for (int i = threadIdx.x; i < NB; i += 256)
        HT[(size_t)i * NCH + c] = h[i];
}

__global__ void k_scan_chunks(const int* __restrict__ HT, int* __restrict__ OFS,
                              int* __restrict__ T) {
    int b = blockIdx.x;
    int lane = threadIdx.x;  // 64
    const int* hb = HT + (size_t)b * NCH;
    int run = 0;
    for (int c0 = 0; c0 < NCH; c0 += 64) {
        int idx = c0 + lane;
        int v = (idx < NCH) ? hb[idx] : 0;
        int inc = v;
#pragma unroll
        for (int d = 1; d < 64; d <<= 1) {
            int t = __shfl_up(inc, d);
            if (lane >= d) inc += t;
        }
        if (idx < NCH) OFS[(size_t)idx * NB + b] = run + inc - v;
        run += __shfl(inc, 63);
    }
    if (lane == 0) T[b] = run;
}

__global__ void k_scan_base(const int* __restrict__ T, int* __restrict__ base,
                            int* __restrict__ row_ofs) {
    int lane = threadIdx.x;  // 64
    int run = 0;
    for (int c0 = 0; c0 < NB; c0 += 64) {
        int idx = c0 + lane;
        int v = (idx < NB) ? T[idx] : 0;
        int inc = v;
#pragma unroll
        for (int d = 1; d < 64; d <<= 1) {
            int t = __shfl_up(inc, d);
            if (lane >= d) inc += t;
        }
        if (idx < NB) base[idx] = run + inc - v;
        run += __shfl(inc, 63);
    }
    if (lane == 0) { base[NB] = run; row_ofs[N_NODES] = run; }
}

__global__ __launch_bounds__(256) void k_partition(const int* __restrict__ rows,
                                                   const int* __restrict__ cols,
                                                   const float* __restrict__ vals,
                                                   const int* __restrict__ OFS,
                                                   const int* __restrict__ base,
                                                   int2* __restrict__ stage) {
    __shared__ int cur[NB];
    int c = blockIdx.x;
    for (int i = threadIdx.x; i < NB; i += 256)
        cur[i] = base[i] + OFS[(size_t)c * NB + i];
    __syncthreads();
    int e0 = c * CHUNK;
    int eend = e0 + CHUNK; if (eend > N_EDGES) eend = N_EDGES;
    for (int e = e0 + threadIdx.x; e < eend; e += 256) {
        int r = rows[e];
        int p = atomicAdd(&cur[r >> 6], 1);
        stage[p] = make_int2(((r & 63) << 17) | cols[e], __float_as_int(vals[e]));
    }
}

// within-bucket row sort, 8-deep pipelined both passes
__global__ __launch_bounds__(256) void k_csr(const int2* __restrict__ stage,
                                             const int* __restrict__ base,
                                             int* __restrict__ row_ofs,
                                             int2* __restrict__ csr) {
    __shared__ int cnt[RPB];
    __shared__ int cur[RPB];
    int b = blockIdx.x, t = threadIdx.x;
    int s = base[b], e = base[b + 1];
    if (t < RPB) cnt[t] = 0;
    __syncthreads();
    {
        int i = s + t;
        for (; i + 7 * 256 < e; i += 8 * 256) {
            int rl[8];
#pragma unroll
            for (int u = 0; u < 8; ++u)
                rl[u] = ((unsigned)stage[i + u * 256].x) >> 17;
#pragma unroll
            for (int u = 0; u < 8; ++u) atomicAdd(&cnt[rl[u]], 1);
        }
        for (; i < e; i += 256)
            atomicAdd(&cnt[((unsigned)stage[i].x) >> 17], 1);
    }
    __syncthreads();
    if (t < 64) {
        int v = cnt[t];
        int inc = v;
#pragma unroll
        for (int d = 1; d < 64; d <<= 1) {
            int u = __shfl_up(inc, d);
            if (t >= d) inc += u;
        }
        int ex = s + inc - v;
        int n = b * RPB + t;
        if (n < N_NODES) row_ofs[n] = ex;
        cur[t] = ex;
    }
    __syncthreads();
    {
        int i = s + t;
        for (; i + 7 * 256 < e; i += 8 * 256) {
            int2 ev[8];
#pragma unroll
            for (int u = 0; u < 8; ++u) ev[u] = stage[i + u * 256];
            int p[8];
#pragma unroll
            for (int u = 0; u < 8; ++u)
                p[u] = atomicAdd(&cur[((unsigned)ev[u].x) >> 17], 1);
#pragma unroll
            for (int u = 0; u < 8; ++u)
                csr[p[u]] = make_int2(ev[u].x & 0x1FFFF, ev[u].y);
        }
        for (; i < e; i += 256) {
            int2 ev = stage[i];
            int p = atomicAdd(&cur[((unsigned)ev.x) >> 17], 1);
            csr[p] = make_int2(ev.x & 0x1FFFF, ev.y);
        }
    }
}

// ---------------------------------------------------------------------------
// SpMM 1: 16-deep pipelined gather of bf16 A rows (256 B/edge).
// ---------------------------------------------------------------------------
__global__ __launch_bounds__(256) void k_spmm1(const unsigned* __restrict__ A32,
                                               const int* __restrict__ row_ofs,
                                               const int2* __restrict__ csr,
                                               unsigned* __restrict__ S1a,
                                               float2* __restrict__ S1r) {
    int wv = threadIdx.x >> 6, lane = threadIdx.x & 63;
    int node = blockIdx.x * 4 + wv;
    if (node >= N_NODES) return;
    int s = row_ofs[node], e = row_ofs[node + 1];
    float a0 = 0.f, a1 = 0.f;
    int t = s;
    for (; t + 16 <= e; t += 16) {
        int2 cv[16];
#pragma unroll
        for (int u = 0; u < 16; ++u) cv[u] = csr[t + u];
        unsigned p[16];
#pragma unroll
        for (int u = 0; u < 16; ++u) p[u] = A32[cv[u].x * 64 + lane];
#pragma unroll
        for (int u = 0; u < 16; ++u) {
            float v = __int_as_float(cv[u].y);
            a0 += v * bf2f(p[u] & 0xffffu);
            a1 += v * bf2f(p[u] >> 16);
        }
    }
    for (; t + 4 <= e; t += 4) {
        int2 cv[4];
#pragma unroll
        for (int u = 0; u < 4; ++u) cv[u] = csr[t + u];
        unsigned p[4];
#pragma unroll
        for (int u = 0; u < 4; ++u) p[u] = A32[cv[u].x * 64 + lane];
#pragma unroll
        for (int u = 0; u < 4; ++u) {
            float v = __int_as_float(cv[u].y);
            a0 += v * bf2f(p[u] & 0xffffu);
            a1 += v * bf2f(p[u] >> 16);
        }
    }
    for (; t < e; ++t) {
        int2 cv = csr[t];
        unsigned p = A32[cv.x * 64 + lane];
        float v = __int_as_float(cv.y);
        a0 += v * bf2f(p & 0xffffu);
        a1 += v * bf2f(p >> 16);
    }
    if (lane < 32)
        S1a[node * 32 + lane] = (unsigned)f2bf(a0) | ((unsigned)f2bf(a1) << 16);
    else
        S1r[node * 32 + (lane - 32)] = make_float2(a0, a1);
}

// ---------------------------------------------------------------------------
// SpMM 2 + fused epilogue: 16-deep pipelined gather of bf16 S1a rows (128 B/edge)
// ---------------------------------------------------------------------------
__global__ __launch_bounds__(256) void k_spmm2_out(const unsigned short* __restrict__ S1a16,
                                                   const float* __restrict__ S1r,
                                                   const int* __restrict__ row_ofs,
                                                   const int2* __restrict__ csr,
                                                   const float* __restrict__ c2,
                                                   const float* __restrict__ cr,
                                                   const float* __restrict__ b2,
                                                   float* __restrict__ out) {
    int wv = threadIdx.x >> 6, lane = threadIdx.x & 63;
    int node = blockIdx.x * 4 + wv;
    if (node >= N_NODES) return;
    int s = row_ofs[node], e = row_ofs[node + 1];
    float acc = 0.f, rsum = 0.f;
    int t = s;
    for (; t + 16 <= e; t += 16) {
        int2 cv[16];
#pragma unroll
        for (int u = 0; u < 16; ++u) cv[u] = csr[t + u];
        unsigned short p[16];
#pragma unroll
        for (int u = 0; u < 16; ++u) p[u] = S1a16[cv[u].x * 64 + lane];
#pragma unroll
        for (int u = 0; u < 16; ++u) {
            float v = __int_as_float(cv[u].y);
            rsum += v;
            acc += v * bf2f((unsigned)p[u]);
        }
    }
    for (; t + 4 <= e; t += 4) {
        int2 cv[4];
#pragma unroll
        for (int u = 0; u < 4; ++u) cv[u] = csr[t + u];
        unsigned short p[4];
#pragma unroll
        for (int u = 0; u < 4; ++u) p[u] = S1a16[cv[u].x * 64 + lane];
#pragma unroll
        for (int u = 0; u < 4; ++u) {
            float v = __int_as_float(cv[u].y);
            rsum += v;
            acc += v * bf2f((unsigned)p[u]);
        }
    }
    for (; t < e; ++t) {
        int2 cv = csr[t];
        float v = __int_as_float(cv.y);
        rsum += v;
        acc += v * bf2f((unsigned)S1a16[cv.x * 64 + lane]);
    }
    float o = acc + rsum * c2[lane] + b2[lane];
    float res = S1r[node * 64 + lane] + cr[lane];
    out[node * 64 + lane] = fmaxf(o, 0.f) + res;
}

// ---------------------------------------------------------------------------
extern "C" void kernel_launch(void* const* d_in, const int* in_sizes, int n_in,
                              void* d_out, int out_size, void* d_ws, size_t ws_size,
                              hipStream_t stream) {
    const float* x        = (const float*)d_in[0];
    const int*   adj_rows = (const int*)d_in[1];
    const int*   adj_cols = (const int*)d_in[2];
    const float* adj_vals = (const float*)d_in[3];
    const float* W1       = (const float*)d_in[4];
    const float* b1       = (const float*)d_in[5];
    const float* W2       = (const float*)d_in[6];
    const float* b2       = (const float*)d_in[7];
    const float* Wres     = (const float*)d_in[8];
    const float* bres     = (const float*)d_in[9];
    float* out = (float*)d_out;

    char* ws = (char*)d_ws;
    size_t off = 0;
    auto alloc = [&](size_t bytes) {
        size_t o = off;
        off += (bytes + 511) & ~511ULL;
        return o;
    };

    unsigned short* WT  = (unsigned short*)(ws + alloc((size_t)NFEAT * FCAT * 2));
    float* c2           = (float*)(ws + alloc(NCLASS * 4));
    float* cr           = (float*)(ws + alloc(NCLASS * 4));
    // stage (CSR build) and A (GEMM/spmm1) time-share one 25.6 MB buffer
    char* unionbuf      = ws + alloc((size_t)N_EDGES * 8);
    int2* stage         = (int2*)unionbuf;
    unsigned short* A   = (unsigned short*)unionbuf;
    unsigned* S1a       = (unsigned*)(ws + alloc((size_t)N_NODES * 32 * 4));
    // S1r region time-shares with HT/OFS (dead after k_partition)
    char* s1r_region    = ws + alloc((size_t)N_NODES * 64 * 4);
    float* S1r          = (float*)s1r_region;
    int*   HT           = (int*)s1r_region;
    int*   OFS          = (int*)(s1r_region + (((size_t)NB * NCH * 4 + 511) & ~511ULL));
    int*   T            = (int*)(ws + alloc((size_t)NB * 4));
    int*   base         = (int*)(ws + alloc((size_t)(NB + 1) * 4));
    int*   row_ofs      = (int*)(ws + alloc((size_t)(N_NODES + 1) * 4));
    int2*  csr          = (int2*)(ws + alloc((size_t)N_EDGES * 8));
    (void)ws_size; (void)in_sizes; (void)n_in; (void)out_size;

    // weight prep (tiny)
    k_prep_wcat<<<NFEAT, FCAT, 0, stream>>>(W1, W2, Wres, WT);
    k_prep_c<<<1, FCAT, 0, stream>>>(b1, W2, Wres, bres, c2, cr);

    // CSR build: atomic-free partition + within-bucket sort
    k_hist_bkt<<<NCH, 256, 0, stream>>>(adj_rows, HT);
    k_scan_chunks<<<NB, 64, 0, stream>>>(HT, OFS, T);
    k_scan_base<<<1, 64, 0, stream>>>(T, base, row_ofs);
    k_partition<<<NCH, 256, 0, stream>>>(adj_rows, adj_cols, adj_vals, OFS, base, stage);
    k_csr<<<NB, 256, 0, stream>>>(stage, base, row_ofs, csr);

    // dense MFMA GEMM: A = bf16(x @ Wcat)   (overwrites stage)
    k_gemm_a<<<(N_NODES + 63) / 64, 256, 0, stream>>>(x, WT, A);

    // spmm 1: S1 = spmm(A)  (bf16 gather; overwrites HT/OFS region with S1r)
    k_spmm1<<<(N_NODES + 3) / 4, 256, 0, stream>>>((const unsigned*)A, row_ofs, csr,
                                                   S1a, (float2*)S1r);

    // spmm 2 + epilogue
    k_spmm2_out<<<(N_NODES + 3) / 4, 256, 0, stream>>>((const unsigned short*)S1a, S1r,
                                                       row_ofs, csr, c2, cr, b2, out);
}

// Round 10
// 392.678 us; speedup vs baseline: 9.4919x; 1.0351x over previous
//
#include <hip/hip_runtime.h>

#define N_NODES 100000
#define N_EDGES 3200000
#define NFEAT 512
#define NHID 256
#define NCLASS 64
#define FCAT 128   // 2*NCLASS

#define RPB 64                         // rows per bucket
#define NB 1563                        // ceil(N_NODES / RPB)
#define CHUNK 8192                     // edges per partition block
#define NCH 391                        // ceil(N_EDGES / CHUNK)

#define SCA 4194304.0f                 // 2^22 fixed-point scale (|sum|<512)
#define ISCA (1.0f / 4194304.0f)
#define SCR 16777216.0f                // 2^24 for rsum (|sum|<=64)
#define ISCR (1.0f / 16777216.0f)

typedef __attribute__((ext_vector_type(8))) short short8;
typedef __attribute__((ext_vector_type(4))) float f32x4;

static __device__ __forceinline__ unsigned short f2bf(float f) {
    unsigned u = __float_as_uint(f);
    unsigned r = (u + 0x7FFF + ((u >> 16) & 1)) >> 16;  // RNE
    return (unsigned short)r;
}
static __device__ __forceinline__ float bf2f(unsigned s) {
    return __uint_as_float(s << 16);
}
static __device__ __forceinline__ short8 cvt8(float4 x, float4 y) {
    short8 r;
    r[0] = (short)f2bf(x.x); r[1] = (short)f2bf(x.y);
    r[2] = (short)f2bf(x.z); r[3] = (short)f2bf(x.w);
    r[4] = (short)f2bf(y.x); r[5] = (short)f2bf(y.y);
    r[6] = (short)f2bf(y.z); r[7] = (short)f2bf(y.w);
    return r;
}
__device__ __forceinline__ void gload_lds16(const unsigned short* g, unsigned short* l) {
    __builtin_amdgcn_global_load_lds(
        (const __attribute__((address_space(1))) unsigned int*)g,
        (__attribute__((address_space(3))) unsigned int*)l, 16, 0, 0);
}

// ---------------------------------------------------------------------------
// Weight prep
// ---------------------------------------------------------------------------
__global__ void k_prep_wcat(const float* __restrict__ W1, const float* __restrict__ W2,
                            const float* __restrict__ Wres, unsigned short* __restrict__ WT) {
    int k = blockIdx.x;        // 0..511
    int j = threadIdx.x;       // 0..127
    const float* wb = (j < NCLASS) ? W2 : Wres;
    int jj = j & (NCLASS - 1);
    const float* w1row = W1 + (size_t)k * NHID;
    float acc = 0.f;
    for (int m = 0; m < NHID; ++m)
        acc += w1row[m] * wb[(size_t)m * NCLASS + jj];
    WT[(size_t)j * NFEAT + k] = f2bf(acc);
}

__global__ void k_prep_c(const float* __restrict__ b1, const float* __restrict__ W2,
                         const float* __restrict__ Wres, const float* __restrict__ bres,
                         float* __restrict__ c2, float* __restrict__ cr) {
    int j = threadIdx.x;  // 0..127
    const float* wb = (j < NCLASS) ? W2 : Wres;
    int jj = j & (NCLASS - 1);
    float acc = 0.f;
    for (int m = 0; m < NHID; ++m)
        acc += b1[m] * wb[(size_t)m * NCLASS + jj];
    if (j < NCLASS) c2[jj] = acc;
    else            cr[jj] = acc + bres[jj];
}

// ---------------------------------------------------------------------------
// MFMA GEMM: A_bf16[N,128] = bf16(X[N,512] @ Wcat[512,128])
// Direct-A from global f32; B double-buffered in LDS via global_load_lds,
// XOR-swizzled. 1 barrier/step.
// ---------------------------------------------------------------------------
#define GBK 64
__global__ __launch_bounds__(256) void k_gemm_a(const float* __restrict__ X,
                                                const unsigned short* __restrict__ WT,
                                                unsigned short* __restrict__ A) {
    __shared__ __align__(16) unsigned short Bs[2][FCAT * GBK];  // 2 x 16 KB
    int tid = threadIdx.x;
    int lane = tid & 63, w = tid >> 6;
    int lr = lane & 15, ls = lane >> 4;
    int row = blockIdx.x * 64 + w * 16 + lr;
    if (row >= N_NODES) row = N_NODES - 1;  // tail clamp (loads only)
    const float* pA = X + (size_t)row * NFEAT;

#define STAGE(buf, k0)                                                         \
    {                                                                          \
        _Pragma("unroll")                                                      \
        for (int q = 0; q < 4; ++q) {                                          \
            int sidx = q * 256 + tid;                                          \
            int n = sidx >> 3, c8 = sidx & 7;                                  \
            const unsigned short* src =                                        \
                WT + (size_t)n * NFEAT + (k0) + ((c8 ^ (n & 7)) << 3);         \
            unsigned short* dst = &Bs[buf][(size_t)(q * 256 + w * 64) * 8];    \
            gload_lds16(src, dst);                                             \
        }                                                                      \
    }

    f32x4 acc[8] = {};
    STAGE(0, 0);
    __syncthreads();
    int cur = 0;

#pragma unroll
    for (int t = 0; t < 8; ++t) {
        const int k0 = t * GBK;
        float4 a00 = *(const float4*)(pA + k0 + ls * 8);
        float4 a01 = *(const float4*)(pA + k0 + ls * 8 + 4);
        float4 a10 = *(const float4*)(pA + k0 + 32 + ls * 8);
        float4 a11 = *(const float4*)(pA + k0 + 32 + ls * 8 + 4);
        if (t < 7) STAGE(cur ^ 1, k0 + GBK);

        short8 af0 = cvt8(a00, a01);
        short8 af1 = cvt8(a10, a11);
        const unsigned short* bb = &Bs[cur][0];
#pragma unroll
        for (int nf = 0; nf < 8; ++nf) {
            int n = nf * 16 + lr;
            int p0 = ls ^ (n & 7);
            int p1 = (4 + ls) ^ (n & 7);
            short8 b0 = *(const short8*)(bb + (size_t)n * 64 + p0 * 8);
            short8 b1 = *(const short8*)(bb + (size_t)n * 64 + p1 * 8);
            acc[nf] = __builtin_amdgcn_mfma_f32_16x16x32_bf16(af0, b0, acc[nf], 0, 0, 0);
            acc[nf] = __builtin_amdgcn_mfma_f32_16x16x32_bf16(af1, b1, acc[nf], 0, 0, 0);
        }
        __syncthreads();
        cur ^= 1;
    }
#undef STAGE

    // C/D layout: col = lane&15, row = (lane>>4)*4 + j
#pragma unroll
    for (int j = 0; j < 4; ++j) {
        int gr = blockIdx.x * 64 + w * 16 + ls * 4 + j;
        if (gr < N_NODES) {
#pragma unroll
            for (int nf = 0; nf < 8; ++nf)
                A[(size_t)gr * FCAT + nf * 16 + lr] = f2bf(acc[nf][j]);
        }
    }
}

// ---------------------------------------------------------------------------
// Bucket build — atomic-free radix partition (64-row buckets, NO row sort)
// ---------------------------------------------------------------------------
__global__ __launch_bounds__(256) void k_hist_bkt(const int* __restrict__ rows,
                                                  int* __restrict__ HT) {
    __shared__ int h[NB];
    int c = blockIdx.x;
    for (int i = threadIdx.x; i < NB; i += 256) h[i] = 0;
    __syncthreads();
    int e0 = c * CHUNK;
    int eend = e0 + CHUNK; if (eend > N_EDGES) eend = N_EDGES;
    int i = e0 + threadIdx.x;
    for (; i + 7 * 256 < eend; i += 8 * 256) {
        int r[8];
#pragma unroll
        for (int u = 0; u < 8; ++u) r[u] = rows[i + u * 256];
#pragma unroll
        for (int u = 0; u < 8; ++u) atomicAdd(&h[r[u] >> 6], 1);
    }
    for (; i < eend; i += 256)
        atomicAdd(&h[rows[i] >> 6], 1);
    __syncthreads();
    for (int k = threadIdx.x; k < NB; k += 256)
        HT[(size_t)k * NCH + c] = h[k];
}

__global__ void k_scan_chunks(const int* __restrict__ HT, int* __restrict__ OFS,
                              int* __restrict__ T) {
    int b = blockIdx.x;
    int lane = threadIdx.x;  // 64
    const int* hb = HT + (size_t)b * NCH;
    int run = 0;
    for (int c0 = 0; c0 < NCH; c0 += 64) {
        int idx = c0 + lane;
        int v = (idx < NCH) ? hb[idx] : 0;
        int inc = v;
#pragma unroll
        for (int d = 1; d < 64; d <<= 1) {
            int t = __shfl_up(inc, d);
            if (lane >= d) inc += t;
        }
        if (idx < NCH) OFS[(size_t)idx * NB + b] = run + inc - v;
        run += __shfl(inc, 63);
    }
    if (lane == 0) T[b] = run;
}

__global__ void k_scan_base(const int* __restrict__ T, int* __restrict__ base) {
    int lane = threadIdx.x;  // 64
    int run = 0;
    for (int c0 = 0; c0 < NB; c0 += 64) {
        int idx = c0 + lane;
        int v = (idx < NB) ? T[idx] : 0;
        int inc = v;
#pragma unroll
        for (int d = 1; d < 64; d <<= 1) {
            int t = __shfl_up(inc, d);
            if (lane >= d) inc += t;
        }
        if (idx < NB) base[idx] = run + inc - v;
        run += __shfl(inc, 63);
    }
    if (lane == 0) base[NB] = run;
}

__global__ __launch_bounds__(256) void k_partition(const int* __restrict__ rows,
                                                   const int* __restrict__ cols,
                                                   const float* __restrict__ vals,
                                                   const int* __restrict__ OFS,
                                                   const int* __restrict__ base,
                                                   int2* __restrict__ stage) {
    __shared__ int cur[NB];
    int c = blockIdx.x;
    for (int i = threadIdx.x; i < NB; i += 256)
        cur[i] = base[i] + OFS[(size_t)c * NB + i];
    __syncthreads();
    int e0 = c * CHUNK;
    int eend = e0 + CHUNK; if (eend > N_EDGES) eend = N_EDGES;
    int i = e0 + threadIdx.x;
    for (; i + 7 * 256 < eend; i += 8 * 256) {
        int r[8], cc[8]; float v[8];
#pragma unroll
        for (int u = 0; u < 8; ++u) r[u] = rows[i + u * 256];
#pragma unroll
        for (int u = 0; u < 8; ++u) cc[u] = cols[i + u * 256];
#pragma unroll
        for (int u = 0; u < 8; ++u) v[u] = vals[i + u * 256];
        int p[8];
#pragma unroll
        for (int u = 0; u < 8; ++u) p[u] = atomicAdd(&cur[r[u] >> 6], 1);
#pragma unroll
        for (int u = 0; u < 8; ++u)
            stage[p[u]] = make_int2(((r[u] & 63) << 17) | cc[u], __float_as_int(v[u]));
    }
    for (; i < eend; i += 256) {
        int r = rows[i];
        int p = atomicAdd(&cur[r >> 6], 1);
        stage[p] = make_int2(((r & 63) << 17) | cols[i], __float_as_int(vals[i]));
    }
}

// ---------------------------------------------------------------------------
// SpMM 1 over bucket-staged edges: block = bucket, NATIVE int32 fixed-point
// LDS atomics (fire-and-forget ds_add_u32). 16-deep gather of bf16 A rows.
// ---------------------------------------------------------------------------
__global__ __launch_bounds__(256) void k_spmm1(const unsigned* __restrict__ A32,
                                               const int* __restrict__ base,
                                               const int2* __restrict__ stage,
                                               unsigned* __restrict__ S1a,
                                               float2* __restrict__ S1r) {
    __shared__ int acc[RPB][FCAT];  // 32 KB
    int b = blockIdx.x, tid = threadIdx.x;
    int wv = tid >> 6, lane = tid & 63;
    int4* az = (int4*)&acc[0][0];
    for (int i = tid; i < RPB * FCAT / 4; i += 256) az[i] = make_int4(0, 0, 0, 0);
    __syncthreads();

    int s = base[b], e = base[b + 1];
    int per = (e - s + 3) >> 2;
    int ws = s + wv * per;
    int we = ws + per; if (we > e) we = e;
    int t = ws;
    for (; t + 16 <= we; t += 16) {
        int2 cv[16];
#pragma unroll
        for (int u = 0; u < 16; ++u) cv[u] = stage[t + u];
        unsigned p[16];
#pragma unroll
        for (int u = 0; u < 16; ++u)
            p[u] = A32[(size_t)(cv[u].x & 0x1FFFF) * 64 + lane];
#pragma unroll
        for (int u = 0; u < 16; ++u) {
            float vs = __int_as_float(cv[u].y) * SCA;
            int rl = ((unsigned)cv[u].x) >> 17;
            atomicAdd(&acc[rl][lane * 2],     __float2int_rn(vs * bf2f(p[u] & 0xffffu)));
            atomicAdd(&acc[rl][lane * 2 + 1], __float2int_rn(vs * bf2f(p[u] >> 16)));
        }
    }
    for (; t < we; ++t) {
        int2 cv = stage[t];
        unsigned p = A32[(size_t)(cv.x & 0x1FFFF) * 64 + lane];
        float vs = __int_as_float(cv.y) * SCA;
        int rl = ((unsigned)cv.x) >> 17;
        atomicAdd(&acc[rl][lane * 2],     __float2int_rn(vs * bf2f(p & 0xffffu)));
        atomicAdd(&acc[rl][lane * 2 + 1], __float2int_rn(vs * bf2f(p >> 16)));
    }
    __syncthreads();

#pragma unroll
    for (int rr = 0; rr < 16; ++rr) {
        int r = wv * 16 + rr;
        int node = b * RPB + r;
        if (node < N_NODES) {
            if (lane < 32) {
                float a0 = (float)acc[r][lane * 2] * ISCA;
                float a1 = (float)acc[r][lane * 2 + 1] * ISCA;
                S1a[(size_t)node * 32 + lane] =
                    (unsigned)f2bf(a0) | ((unsigned)f2bf(a1) << 16);
            } else {
                int m = lane - 32;
                S1r[(size_t)node * 32 + m] =
                    make_float2((float)acc[r][64 + m * 2] * ISCA,
                                (float)acc[r][64 + m * 2 + 1] * ISCA);
            }
        }
    }
}

// ---------------------------------------------------------------------------
// SpMM 2 + epilogue over bucket-staged edges: 2 edges per wave (32 lanes x
// 64 cols each), int32 fixed-point LDS accumulation, 16 edges per batch.
// ---------------------------------------------------------------------------
__global__ __launch_bounds__(256) void k_spmm2_out(const unsigned* __restrict__ S1a32,
                                                   const float* __restrict__ S1r,
                                                   const int* __restrict__ base,
                                                   const int2* __restrict__ stage,
                                                   const float* __restrict__ c2,
                                                   const float* __restrict__ cr,
                                                   const float* __restrict__ b2,
                                                   float* __restrict__ out) {
    __shared__ int acc[RPB][NCLASS];  // 16 KB
    __shared__ int rs[RPB];
    int b = blockIdx.x, tid = threadIdx.x;
    int wv = tid >> 6, lane = tid & 63;
    int h = lane >> 5, l5 = lane & 31;
    int4* az = (int4*)&acc[0][0];
    for (int i = tid; i < RPB * NCLASS / 4; i += 256) az[i] = make_int4(0, 0, 0, 0);
    if (tid < RPB) rs[tid] = 0;
    __syncthreads();

    int s = base[b], e = base[b + 1];
    int per = (e - s + 3) >> 2;
    int ws = s + wv * per;
    int we = ws + per; if (we > e) we = e;
    int t = ws;
    for (; t + 16 <= we; t += 16) {
        int2 cv[8];
#pragma unroll
        for (int u = 0; u < 8; ++u) cv[u] = stage[t + u * 2 + h];
        unsigned p[8];
#pragma unroll
        for (int u = 0; u < 8; ++u)
            p[u] = S1a32[(size_t)(cv[u].x & 0x1FFFF) * 32 + l5];
#pragma unroll
        for (int u = 0; u < 8; ++u) {
            float v = __int_as_float(cv[u].y);
            float vs = v * SCA;
            int rl = ((unsigned)cv[u].x) >> 17;
            atomicAdd(&acc[rl][l5 * 2],     __float2int_rn(vs * bf2f(p[u] & 0xffffu)));
            atomicAdd(&acc[rl][l5 * 2 + 1], __float2int_rn(vs * bf2f(p[u] >> 16)));
            if (l5 == 0) atomicAdd(&rs[rl], __float2int_rn(v * SCR));
        }
    }
    for (; t < we; t += 2) {
        int idx = t + h;
        bool act = idx < we;
        int2 cv = stage[act ? idx : t];
        unsigned p = S1a32[(size_t)(cv.x & 0x1FFFF) * 32 + l5];
        float v = __int_as_float(cv.y);
        float vs = v * SCA;
        int rl = ((unsigned)cv.x) >> 17;
        if (act) {
            atomicAdd(&acc[rl][l5 * 2],     __float2int_rn(vs * bf2f(p & 0xffffu)));
            atomicAdd(&acc[rl][l5 * 2 + 1], __float2int_rn(vs * bf2f(p >> 16)));
            if (l5 == 0) atomicAdd(&rs[rl], __float2int_rn(v * SCR));
        }
    }
    __syncthreads();

#pragma unroll
    for (int rr = 0; rr < 16; ++rr) {
        int r = wv * 16 + rr;
        int node = b * RPB + r;
        if (node < N_NODES) {
            float facc = (float)acc[r][lane] * ISCA;
            float rsum = (float)rs[r] * ISCR;
            float o = facc + rsum * c2[lane] + b2[lane];
            float res = S1r[(size_t)node * 64 + lane] + cr[lane];
            out[(size_t)node * 64 + lane] = fmaxf(o, 0.f) + res;
        }
    }
}

// ---------------------------------------------------------------------------
extern "C" void kernel_launch(void* const* d_in, const int* in_sizes, int n_in,
                              void* d_out, int out_size, void* d_ws, size_t ws_size,
                              hipStream_t stream) {
    const float* x        = (const float*)d_in[0];
    const int*   adj_rows = (const int*)d_in[1];
    const int*   adj_cols = (const int*)d_in[2];
    const float* adj_vals = (const float*)d_in[3];
    const float* W1       = (const float*)d_in[4];
    const float* b1       = (const float*)d_in[5];
    const float* W2       = (const float*)d_in[6];
    const float* b2       = (const float*)d_in[7];
    const float* Wres     = (const float*)d_in[8];
    const float* bres     = (const float*)d_in[9];
    float* out = (float*)d_out;

    char* ws = (char*)d_ws;
    size_t off = 0;
    auto alloc = [&](size_t bytes) {
        size_t o = off;
        off += (bytes + 511) & ~511ULL;
        return o;
    };

    unsigned short* WT  = (unsigned short*)(ws + alloc((size_t)NFEAT * FCAT * 2));
    float* c2           = (float*)(ws + alloc(NCLASS * 4));
    float* cr           = (float*)(ws + alloc(NCLASS * 4));
    int2* stage         = (int2*)(ws + alloc((size_t)N_EDGES * 8));
    unsigned short* A   = (unsigned short*)(ws + alloc((size_t)N_NODES * FCAT * 2));
    unsigned* S1a       = (unsigned*)(ws + alloc((size_t)N_NODES * 32 * 4));
    // S1r region time-shares with HT/OFS (both dead after k_partition)
    char* s1r_region    = ws + alloc((size_t)N_NODES * 64 * 4);
    float* S1r          = (float*)s1r_region;
    int*   HT           = (int*)s1r_region;
    int*   OFS          = (int*)(s1r_region + (((size_t)NB * NCH * 4 + 511) & ~511ULL));
    int*   T            = (int*)(ws + alloc((size_t)NB * 4));
    int*   base         = (int*)(ws + alloc((size_t)(NB + 1) * 4));
    (void)ws_size; (void)in_sizes; (void)n_in; (void)out_size;

    // weight prep (tiny)
    k_prep_wcat<<<NFEAT, FCAT, 0, stream>>>(W1, W2, Wres, WT);
    k_prep_c<<<1, FCAT, 0, stream>>>(b1, W2, Wres, bres, c2, cr);

    // bucket build: atomic-free radix partition
    k_hist_bkt<<<NCH, 256, 0, stream>>>(adj_rows, HT);
    k_scan_chunks<<<NB, 64, 0, stream>>>(HT, OFS, T);
    k_scan_base<<<1, 64, 0, stream>>>(T, base);
    k_partition<<<NCH, 256, 0, stream>>>(adj_rows, adj_cols, adj_vals, OFS, base, stage);

    // dense MFMA GEMM: A = bf16(x @ Wcat)
    k_gemm_a<<<(N_NODES + 63) / 64, 256, 0, stream>>>(x, WT, A);

    // spmm 1: S1 = spmm(A)  (bf16 gather; int-LDS accumulate; writes S1r over HT/OFS)
    k_spmm1<<<NB, 256, 0, stream>>>((const unsigned*)A, base, stage, S1a, (float2*)S1r);

    // spmm 2 + epilogue
    k_spmm2_out<<<NB, 256, 0, stream>>>((const unsigned*)S1a, S1r, base, stage,
                                        c2, cr, b2, out);
}

// Round 11
// 387.422 us; speedup vs baseline: 9.6207x; 1.0136x over previous
//
#include <hip/hip_runtime.h>

#define N_NODES 100000
#define N_EDGES 3200000
#define NFEAT 512
#define NHID 256
#define NCLASS 64
#define FCAT 128   // 2*NCLASS

#define RPB 32                         // rows per bucket (100000/32 = 3125 exact)
#define NB 3125                        // N_NODES / RPB
#define CHUNK 8192                     // edges per partition block
#define NCH 391                        // ceil(N_EDGES / CHUNK)

// fixed-point scales (magic-number cvt needs |x| < 2^21 per term)
#define SC1 131072.0f                  // 2^17, spmm1 (|v*a| <= ~16)
#define ISC1 (1.0f / 131072.0f)
#define SC2 16384.0f                   // 2^14, spmm2 (|v*s| <= ~128)
#define ISC2 (1.0f / 16384.0f)
#define SCR 1048576.0f                 // 2^20, rsum (v in [0,1])
#define ISCR (1.0f / 1048576.0f)
#define MAGICF 12582912.0f             // 1.5 * 2^23
#define MAGICI 0x4B400000

typedef __attribute__((ext_vector_type(8))) short short8;
typedef __attribute__((ext_vector_type(4))) float f32x4;

static __device__ __forceinline__ unsigned short f2bf(float f) {
    unsigned u = __float_as_uint(f);
    unsigned r = (u + 0x7FFF + ((u >> 16) & 1)) >> 16;  // RNE
    return (unsigned short)r;
}
static __device__ __forceinline__ float bf2f(unsigned s) {
    return __uint_as_float(s << 16);
}
// round-to-nearest-even float -> int via exponent-pinning trick (1 fma + 1 sub)
static __device__ __forceinline__ int f2fix(float vs, float a) {
    return __float_as_int(fmaf(vs, a, MAGICF)) - MAGICI;
}
static __device__ __forceinline__ short8 cvt8(float4 x, float4 y) {
    short8 r;
    r[0] = (short)f2bf(x.x); r[1] = (short)f2bf(x.y);
    r[2] = (short)f2bf(x.z); r[3] = (short)f2bf(x.w);
    r[4] = (short)f2bf(y.x); r[5] = (short)f2bf(y.y);
    r[6] = (short)f2bf(y.z); r[7] = (short)f2bf(y.w);
    return r;
}
__device__ __forceinline__ void gload_lds16(const unsigned short* g, unsigned short* l) {
    __builtin_amdgcn_global_load_lds(
        (const __attribute__((address_space(1))) unsigned int*)g,
        (__attribute__((address_space(3))) unsigned int*)l, 16, 0, 0);
}

// ---------------------------------------------------------------------------
// Weight prep
// ---------------------------------------------------------------------------
__global__ void k_prep_wcat(const float* __restrict__ W1, const float* __restrict__ W2,
                            const float* __restrict__ Wres, unsigned short* __restrict__ WT) {
    int k = blockIdx.x;        // 0..511
    int j = threadIdx.x;       // 0..127
    const float* wb = (j < NCLASS) ? W2 : Wres;
    int jj = j & (NCLASS - 1);
    const float* w1row = W1 + (size_t)k * NHID;
    float acc = 0.f;
    for (int m = 0; m < NHID; ++m)
        acc += w1row[m] * wb[(size_t)m * NCLASS + jj];
    WT[(size_t)j * NFEAT + k] = f2bf(acc);
}

__global__ void k_prep_c(const float* __restrict__ b1, const float* __restrict__ W2,
                         const float* __restrict__ Wres, const float* __restrict__ bres,
                         float* __restrict__ c2, float* __restrict__ cr) {
    int j = threadIdx.x;  // 0..127
    const float* wb = (j < NCLASS) ? W2 : Wres;
    int jj = j & (NCLASS - 1);
    float acc = 0.f;
    for (int m = 0; m < NHID; ++m)
        acc += b1[m] * wb[(size_t)m * NCLASS + jj];
    if (j < NCLASS) c2[jj] = acc;
    else            cr[jj] = acc + bres[jj];
}

// ---------------------------------------------------------------------------
// MFMA GEMM: A2[N][64] uint = pack{bf16 col c, bf16 col c+64} of X @ Wcat
// Direct-A from global f32; B double-buffered in LDS via global_load_lds,
// XOR-swizzled. 1 barrier/step.
// ---------------------------------------------------------------------------
#define GBK 64
__global__ __launch_bounds__(256) void k_gemm_a(const float* __restrict__ X,
                                                const unsigned short* __restrict__ WT,
                                                unsigned* __restrict__ A2) {
    __shared__ __align__(16) unsigned short Bs[2][FCAT * GBK];  // 2 x 16 KB
    int tid = threadIdx.x;
    int lane = tid & 63, w = tid >> 6;
    int lr = lane & 15, ls = lane >> 4;
    int row = blockIdx.x * 64 + w * 16 + lr;
    if (row >= N_NODES) row = N_NODES - 1;  // tail clamp (loads only)
    const float* pA = X + (size_t)row * NFEAT;

#define STAGE(buf, k0)                                                         \
    {                                                                          \
        _Pragma("unroll")                                                      \
        for (int q = 0; q < 4; ++q) {                                          \
            int sidx = q * 256 + tid;                                          \
            int n = sidx >> 3, c8 = sidx & 7;                                  \
            const unsigned short* src =                                        \
                WT + (size_t)n * NFEAT + (k0) + ((c8 ^ (n & 7)) << 3);         \
            unsigned short* dst = &Bs[buf][(size_t)(q * 256 + w * 64) * 8];    \
            gload_lds16(src, dst);                                             \
        }                                                                      \
    }

    f32x4 acc[8] = {};
    STAGE(0, 0);
    __syncthreads();
    int cur = 0;

#pragma unroll
    for (int t = 0; t < 8; ++t) {
        const int k0 = t * GBK;
        float4 a00 = *(const float4*)(pA + k0 + ls * 8);
        float4 a01 = *(const float4*)(pA + k0 + ls * 8 + 4);
        float4 a10 = *(const float4*)(pA + k0 + 32 + ls * 8);
        float4 a11 = *(const float4*)(pA + k0 + 32 + ls * 8 + 4);
        if (t < 7) STAGE(cur ^ 1, k0 + GBK);

        short8 af0 = cvt8(a00, a01);
        short8 af1 = cvt8(a10, a11);
        const unsigned short* bb = &Bs[cur][0];
#pragma unroll
        for (int nf = 0; nf < 8; ++nf) {
            int n = nf * 16 + lr;
            int p0 = ls ^ (n & 7);
            int p1 = (4 + ls) ^ (n & 7);
            short8 b0 = *(const short8*)(bb + (size_t)n * 64 + p0 * 8);
            short8 b1 = *(const short8*)(bb + (size_t)n * 64 + p1 * 8);
            acc[nf] = __builtin_amdgcn_mfma_f32_16x16x32_bf16(af0, b0, acc[nf], 0, 0, 0);
            acc[nf] = __builtin_amdgcn_mfma_f32_16x16x32_bf16(af1, b1, acc[nf], 0, 0, 0);
        }
        __syncthreads();
        cur ^= 1;
    }
#undef STAGE

    // C/D layout: col = lane&15, row = (lane>>4)*4 + j. Pair cols (c, c+64).
#pragma unroll
    for (int j = 0; j < 4; ++j) {
        int gr = blockIdx.x * 64 + w * 16 + ls * 4 + j;
        if (gr < N_NODES) {
#pragma unroll
            for (int nf = 0; nf < 4; ++nf) {
                unsigned lo = f2bf(acc[nf][j]);
                unsigned hi = f2bf(acc[nf + 4][j]);
                A2[(size_t)gr * 64 + nf * 16 + lr] = lo | (hi << 16);
            }
        }
    }
}

// ---------------------------------------------------------------------------
// Bucket build — atomic-free radix partition (32-row buckets)
// ---------------------------------------------------------------------------
__global__ __launch_bounds__(256) void k_hist_bkt(const int* __restrict__ rows,
                                                  int* __restrict__ HT) {
    __shared__ int h[NB];
    int c = blockIdx.x;
    for (int i = threadIdx.x; i < NB; i += 256) h[i] = 0;
    __syncthreads();
    int e0 = c * CHUNK;
    int eend = e0 + CHUNK; if (eend > N_EDGES) eend = N_EDGES;
    int i = e0 + threadIdx.x;
    for (; i + 7 * 256 < eend; i += 8 * 256) {
        int r[8];
#pragma unroll
        for (int u = 0; u < 8; ++u) r[u] = rows[i + u * 256];
#pragma unroll
        for (int u = 0; u < 8; ++u) atomicAdd(&h[r[u] >> 5], 1);
    }
    for (; i < eend; i += 256)
        atomicAdd(&h[rows[i] >> 5], 1);
    __syncthreads();
    for (int k = threadIdx.x; k < NB; k += 256)
        HT[(size_t)k * NCH + c] = h[k];
}

__global__ void k_scan_chunks(const int* __restrict__ HT, int* __restrict__ OFS,
                              int* __restrict__ T) {
    int b = blockIdx.x;
    int lane = threadIdx.x;  // 64
    const int* hb = HT + (size_t)b * NCH;
    int run = 0;
    for (int c0 = 0; c0 < NCH; c0 += 64) {
        int idx = c0 + lane;
        int v = (idx < NCH) ? hb[idx] : 0;
        int inc = v;
#pragma unroll
        for (int d = 1; d < 64; d <<= 1) {
            int t = __shfl_up(inc, d);
            if (lane >= d) inc += t;
        }
        if (idx < NCH) OFS[(size_t)idx * NB + b] = run + inc - v;
        run += __shfl(inc, 63);
    }
    if (lane == 0) T[b] = run;
}

__global__ void k_scan_base(const int* __restrict__ T, int* __restrict__ base) {
    int lane = threadIdx.x;  // 64
    int run = 0;
    for (int c0 = 0; c0 < NB; c0 += 64) {
        int idx = c0 + lane;
        int v = (idx < NB) ? T[idx] : 0;
        int inc = v;
#pragma unroll
        for (int d = 1; d < 64; d <<= 1) {
            int t = __shfl_up(inc, d);
            if (lane >= d) inc += t;
        }
        if (idx < NB) base[idx] = run + inc - v;
        run += __shfl(inc, 63);
    }
    if (lane == 0) base[NB] = run;
}

__global__ __launch_bounds__(256) void k_partition(const int* __restrict__ rows,
                                                   const int* __restrict__ cols,
                                                   const float* __restrict__ vals,
                                                   const int* __restrict__ OFS,
                                                   const int* __restrict__ base,
                                                   int2* __restrict__ stage) {
    __shared__ int cur[NB];
    int c = blockIdx.x;
    for (int i = threadIdx.x; i < NB; i += 256)
        cur[i] = base[i] + OFS[(size_t)c * NB + i];
    __syncthreads();
    int e0 = c * CHUNK;
    int eend = e0 + CHUNK; if (eend > N_EDGES) eend = N_EDGES;
    int i = e0 + threadIdx.x;
    for (; i + 7 * 256 < eend; i += 8 * 256) {
        int r[8], cc[8]; float v[8];
#pragma unroll
        for (int u = 0; u < 8; ++u) r[u] = rows[i + u * 256];
#pragma unroll
        for (int u = 0; u < 8; ++u) cc[u] = cols[i + u * 256];
#pragma unroll
        for (int u = 0; u < 8; ++u) v[u] = vals[i + u * 256];
        int p[8];
#pragma unroll
        for (int u = 0; u < 8; ++u) p[u] = atomicAdd(&cur[r[u] >> 5], 1);
#pragma unroll
        for (int u = 0; u < 8; ++u)
            stage[p[u]] = make_int2(((r[u] & 31) << 17) | cc[u], __float_as_int(v[u]));
    }
    for (; i < eend; i += 256) {
        int r = rows[i];
        int p = atomicAdd(&cur[r >> 5], 1);
        stage[p] = make_int2(((r & 31) << 17) | cols[i], __float_as_int(vals[i]));
    }
}

// ---------------------------------------------------------------------------
// SpMM 1 over bucket-staged edges: block = bucket (32 rows), int32 fixed-point
// LDS atomics, conflict-free pair layout (lane -> cols lane, lane+64).
// ---------------------------------------------------------------------------
__global__ __launch_bounds__(256) void k_spmm1(const unsigned* __restrict__ A2,
                                               const int* __restrict__ base,
                                               const int2* __restrict__ stage,
                                               unsigned short* __restrict__ S1a,
                                               float* __restrict__ S1r) {
    __shared__ int acc[RPB][FCAT];  // 16 KB
    int b = blockIdx.x, tid = threadIdx.x;
    int wv = tid >> 6, lane = tid & 63;
    int4* az = (int4*)&acc[0][0];
    for (int i = tid; i < RPB * FCAT / 4; i += 256) az[i] = make_int4(0, 0, 0, 0);
    __syncthreads();

    int s = base[b], e = base[b + 1];
    int per = (e - s + 3) >> 2;
    int ws = s + wv * per;
    int we = ws + per; if (we > e) we = e;
    int t = ws;
    for (; t + 16 <= we; t += 16) {
        int2 cv[16];
#pragma unroll
        for (int u = 0; u < 16; ++u) cv[u] = stage[t + u];
        unsigned p[16];
#pragma unroll
        for (int u = 0; u < 16; ++u)
            p[u] = A2[(size_t)(cv[u].x & 0x1FFFF) * 64 + lane];
#pragma unroll
        for (int u = 0; u < 16; ++u) {
            float vs = __int_as_float(cv[u].y) * SC1;
            int rl = ((unsigned)cv[u].x) >> 17;
            atomicAdd(&acc[rl][lane],      f2fix(vs, bf2f(p[u] & 0xffffu)));
            atomicAdd(&acc[rl][lane + 64], f2fix(vs, bf2f(p[u] >> 16)));
        }
    }
    for (; t < we; ++t) {
        int2 cv = stage[t];
        unsigned p = A2[(size_t)(cv.x & 0x1FFFF) * 64 + lane];
        float vs = __int_as_float(cv.y) * SC1;
        int rl = ((unsigned)cv.x) >> 17;
        atomicAdd(&acc[rl][lane],      f2fix(vs, bf2f(p & 0xffffu)));
        atomicAdd(&acc[rl][lane + 64], f2fix(vs, bf2f(p >> 16)));
    }
    __syncthreads();

    // acc[r][c] holds col c (linear). col lane -> S1a pair slot; col lane+64 -> S1r.
#pragma unroll
    for (int rr = 0; rr < 8; ++rr) {
        int r = wv * 8 + rr;
        int node = b * RPB + r;   // always < N_NODES (3125*32 = 100000)
        float c0 = (float)acc[r][lane] * ISC1;
        float c1 = (float)acc[r][lane + 64] * ISC1;
        // S1a packed as {col c, col c+32} per uint: col l -> ushort idx (l&31)*2 + (l>>5)
        S1a[(size_t)node * 64 + (lane & 31) * 2 + (lane >> 5)] = f2bf(c0);
        S1r[(size_t)node * 64 + lane] = c1;
    }
}

// ---------------------------------------------------------------------------
// SpMM 2 + epilogue: 2 edges/wave (32 lanes x pair {c, c+32}), conflict-free.
// ---------------------------------------------------------------------------
__global__ __launch_bounds__(256) void k_spmm2_out(const unsigned* __restrict__ S1aP,
                                                   const float* __restrict__ S1r,
                                                   const int* __restrict__ base,
                                                   const int2* __restrict__ stage,
                                                   const float* __restrict__ c2,
                                                   const float* __restrict__ cr,
                                                   const float* __restrict__ b2,
                                                   float* __restrict__ out) {
    __shared__ int acc[RPB][NCLASS];  // 8 KB
    __shared__ int rs[RPB];
    int b = blockIdx.x, tid = threadIdx.x;
    int wv = tid >> 6, lane = tid & 63;
    int h = lane >> 5, l5 = lane & 31;
    int4* az = (int4*)&acc[0][0];
    for (int i = tid; i < RPB * NCLASS / 4; i += 256) az[i] = make_int4(0, 0, 0, 0);
    if (tid < RPB) rs[tid] = 0;
    __syncthreads();

    int s = base[b], e = base[b + 1];
    int per = (e - s + 3) >> 2;
    int ws = s + wv * per;
    int we = ws + per; if (we > e) we = e;
    int t = ws;
    for (; t + 16 <= we; t += 16) {
        int2 cv[8];
#pragma unroll
        for (int u = 0; u < 8; ++u) cv[u] = stage[t + u * 2 + h];
        unsigned p[8];
#pragma unroll
        for (int u = 0; u < 8; ++u)
            p[u] = S1aP[(size_t)(cv[u].x & 0x1FFFF) * 32 + l5];
#pragma unroll
        for (int u = 0; u < 8; ++u) {
            float v = __int_as_float(cv[u].y);
            float vs = v * SC2;
            int rl = ((unsigned)cv[u].x) >> 17;
            atomicAdd(&acc[rl][l5],      f2fix(vs, bf2f(p[u] & 0xffffu)));
            atomicAdd(&acc[rl][l5 + 32], f2fix(vs, bf2f(p[u] >> 16)));
            if (l5 == 0) atomicAdd(&rs[rl], f2fix(v, SCR));
        }
    }
    for (; t < we; t += 2) {
        int idx = t + h;
        bool act = idx < we;
        int2 cv = stage[act ? idx : t];
        unsigned p = S1aP[(size_t)(cv.x & 0x1FFFF) * 32 + l5];
        float v = __int_as_float(cv.y);
        float vs = v * SC2;
        int rl = ((unsigned)cv.x) >> 17;
        if (act) {
            atomicAdd(&acc[rl][l5],      f2fix(vs, bf2f(p & 0xffffu)));
            atomicAdd(&acc[rl][l5 + 32], f2fix(vs, bf2f(p >> 16)));
            if (l5 == 0) atomicAdd(&rs[rl], f2fix(v, SCR));
        }
    }
    __syncthreads();

#pragma unroll
    for (int rr = 0; rr < 8; ++rr) {
        int r = wv * 8 + rr;
        int node = b * RPB + r;   // always < N_NODES
        float facc = (float)acc[r][lane] * ISC2;
        float rsum = (float)rs[r] * ISCR;
        float o = facc + rsum * c2[lane] + b2[lane];
        float res = S1r[(size_t)node * 64 + lane] + cr[lane];
        out[(size_t)node * 64 + lane] = fmaxf(o, 0.f) + res;
    }
}

// ---------------------------------------------------------------------------
extern "C" void kernel_launch(void* const* d_in, const int* in_sizes, int n_in,
                              void* d_out, int out_size, void* d_ws, size_t ws_size,
                              hipStream_t stream) {
    const float* x        = (const float*)d_in[0];
    const int*   adj_rows = (const int*)d_in[1];
    const int*   adj_cols = (const int*)d_in[2];
    const float* adj_vals = (const float*)d_in[3];
    const float* W1       = (const float*)d_in[4];
    const float* b1       = (const float*)d_in[5];
    const float* W2       = (const float*)d_in[6];
    const float* b2       = (const float*)d_in[7];
    const float* Wres     = (const float*)d_in[8];
    const float* bres     = (const float*)d_in[9];
    float* out = (float*)d_out;

    char* ws = (char*)d_ws;
    size_t off = 0;
    auto alloc = [&](size_t bytes) {
        size_t o = off;
        off += (bytes + 511) & ~511ULL;
        return o;
    };

    unsigned short* WT  = (unsigned short*)(ws + alloc((size_t)NFEAT * FCAT * 2));
    float* c2           = (float*)(ws + alloc(NCLASS * 4));
    float* cr           = (float*)(ws + alloc(NCLASS * 4));
    int2* stage         = (int2*)(ws + alloc((size_t)N_EDGES * 8));
    unsigned* A2        = (unsigned*)(ws + alloc((size_t)N_NODES * 64 * 4));
    unsigned* S1a       = (unsigned*)(ws + alloc((size_t)N_NODES * 32 * 4));
    // S1r region time-shares with HT/OFS (both dead after k_partition)
    char* s1r_region    = ws + alloc((size_t)N_NODES * 64 * 4);
    float* S1r          = (float*)s1r_region;
    int*   HT           = (int*)s1r_region;
    int*   OFS          = (int*)(s1r_region + (((size_t)NB * NCH * 4 + 511) & ~511ULL));
    int*   T            = (int*)(ws + alloc((size_t)NB * 4));
    int*   base         = (int*)(ws + alloc((size_t)(NB + 1) * 4));
    (void)ws_size; (void)in_sizes; (void)n_in; (void)out_size;

    // weight prep (tiny)
    k_prep_wcat<<<NFEAT, FCAT, 0, stream>>>(W1, W2, Wres, WT);
    k_prep_c<<<1, FCAT, 0, stream>>>(b1, W2, Wres, bres, c2, cr);

    // bucket build: atomic-free radix partition
    k_hist_bkt<<<NCH, 256, 0, stream>>>(adj_rows, HT);
    k_scan_chunks<<<NB, 64, 0, stream>>>(HT, OFS, T);
    k_scan_base<<<1, 64, 0, stream>>>(T, base);
    k_partition<<<NCH, 256, 0, stream>>>(adj_rows, adj_cols, adj_vals, OFS, base, stage);

    // dense MFMA GEMM: A2 = pair-packed bf16(x @ Wcat)
    k_gemm_a<<<(N_NODES + 63) / 64, 256, 0, stream>>>(x, WT, A2);

    // spmm 1 (writes S1r over dead HT/OFS region)
    k_spmm1<<<NB, 256, 0, stream>>>(A2, base, stage, (unsigned short*)S1a, S1r);

    // spmm 2 + epilogue
    k_spmm2_out<<<NB, 256, 0, stream>>>(S1a, S1r, base, stage, c2, cr, b2, out);
}